// Round 11
// baseline (204.818 us; speedup 1.0000x reference)
//
#include <hip/hip_runtime.h>
#include <math.h>

#define BB 2
#define NN 2048
#define HID 896
#define HQ 14
#define HKV 2
#define DD 64
#define QKV_COLS 1152
#define QSCALE 0.18033688011112042f   // 0.125 * log2(e), folded into Q

typedef __bf16 bf16x8 __attribute__((ext_vector_type(8)));
typedef float f32x4 __attribute__((ext_vector_type(4)));
typedef float f32x16 __attribute__((ext_vector_type(16)));
typedef uint u32x4 __attribute__((ext_vector_type(4)));

__device__ inline ushort f2bs(float f) {   // fp32 -> bf16 (RNE), finite inputs
  uint u = __builtin_bit_cast(uint, f);
  u += 0x7FFFu + ((u >> 16) & 1u);
  return (ushort)(u >> 16);
}
__device__ inline float bs2f(ushort u) {
  return __builtin_bit_cast(float, (uint)u << 16);
}

__device__ inline void gload16(const ushort* g, ushort* l) {
  __builtin_amdgcn_global_load_lds(
      (const __attribute__((address_space(1))) uint*)g,
      (__attribute__((address_space(3))) uint*)l, 16, 0, 0);
}

// packed f32x2 -> bf16x2 (RNE), single VALU op
__device__ inline uint cvtpk(float lo, float hi) {
  uint d;
  asm("v_cvt_pk_bf16_f32 %0, %1, %2" : "=v"(d) : "v"(lo), "v"(hi));
  return d;
}
// v_permlane32_swap_b32 vdst, vsrc:
//   new vdst[32:63] = old vsrc[0:31]; new vsrc[0:31] = old vdst[32:63]
__device__ inline void perm32swap(uint& a, uint& b) {
  asm("v_permlane32_swap_b32 %0, %1" : "+v"(a), "+v"(b));
}

// ---------------------------------------------------------------------------
// Fragment-order layouts (verified round 7): Q/K as [head][tile m][s][lane][8]
// where lane = hi*32+lo holds X[n = m*32+lo][d = s*16+hi*8+e]. V as
// [head][tile m][g][lane][8], g = d*2+w, lane holds V^T[dout = d*32+lo]
// [n = m*32 + w*16 + hi*8 + e]. Attn loads: base + lane*16B, 4KB/tile.
//
// NOTE (rounds 8-9 lesson): the attn inner loop MUST keep the round-7 shape —
// prefetch into nK/nV, vmcnt(0), then COPY into rK/rV before compute. Both
// "ping-pong" variants that computed directly from asm-defined buffers
// corrupted K/V (allocator aliasing of in-flight asm outputs). The 32 movs
// per tile are the price of correctness under this compiler.
// ---------------------------------------------------------------------------

// ---------------------------------------------------------------------------
// prep: [0,3584) cast hidden->bf16 | [3584,4592) qkv-w pack | [4592,5376) o-w
// pack | [5376,5888) rope cos/sin table | [5888,5893) bias pack
// ---------------------------------------------------------------------------
__global__ __launch_bounds__(256)
void prep_kernel(const float* __restrict__ hid, const int* __restrict__ pos,
                 const float* __restrict__ qw, const float* __restrict__ kw,
                 const float* __restrict__ vw, const float* __restrict__ ow,
                 const float* __restrict__ qb, const float* __restrict__ kb,
                 const float* __restrict__ vb,
                 ushort* __restrict__ Ah, ushort* __restrict__ WqkvT,
                 ushort* __restrict__ WoT, float2* __restrict__ tab,
                 float* __restrict__ biasQ)
{
  __shared__ float tile[32][33];
  const int blk = blockIdx.x, t = threadIdx.x;
  if (blk < 3584) {
    int i = blk * 256 + t;
    float4 v = ((const float4*)hid)[i];
    ushort4 o;
    o.x = f2bs(v.x); o.y = f2bs(v.y); o.z = f2bs(v.z); o.w = f2bs(v.w);
    ((ushort4*)Ah)[i] = o;
  } else if (blk < 5376) {
    const float* src; int N, n0, drow, k0;
    if (blk < 4592) {
      int idx = blk - 3584;
      int bx = idx % 36; k0 = (idx / 36) * 32;
      if (bx < 28)      { src = qw; N = 896; n0 = bx * 32;        drow = n0; }
      else if (bx < 32) { src = kw; N = 128; n0 = (bx - 28) * 32; drow = 896 + n0; }
      else              { src = vw; N = 128; n0 = (bx - 32) * 32; drow = 1024 + n0; }
    } else {
      int idx = blk - 4592;
      src = ow; N = 896; n0 = (idx % 28) * 32; k0 = (idx / 28) * 32; drow = n0;
    }
    ushort* dst = (blk < 4592) ? WqkvT : WoT;
    const int tx = t & 31, ty = t >> 5;
#pragma unroll
    for (int i = 0; i < 32; i += 8)
      tile[ty + i][tx] = src[(size_t)(k0 + ty + i) * N + n0 + tx];
    __syncthreads();
#pragma unroll
    for (int i = 0; i < 32; i += 8)
      dst[(size_t)(drow + ty + i) * HID + k0 + tx] = f2bs(tile[tx][ty + i]);
  } else if (blk < 5888) {
    int idx = (blk - 5376) * 256 + t;     // 0 .. 131071
    int m = idx >> 5, f = idx & 31;
    float inv = exp2f(-(float)f * (19.9315685693241741f / 32.0f));
    float ang = (float)pos[m] * inv;
    float sv, cv;
    sincosf(ang, &sv, &cv);
    tab[idx] = make_float2(cv, sv);
  } else {
    int i = (blk - 5888) * 256 + t;
    if (i < QKV_COLS)
      biasQ[i] = (i < 896) ? qb[i] : (i < 1024 ? kb[i - 896] : vb[i - 1024]);
  }
}

// ---------------------------------------------------------------------------
// QKV GEMM (64x128 tile, BK=32) with fused bias + RoPE + scatter epilogue.
// grid (9, 64). bx<8: Q/K cols -> rope -> LDS transpose -> FRAGMENT-ORDER
// stores. bx==8: V cols -> LDS transpose -> fragment-order Vf.
// ---------------------------------------------------------------------------
__global__ __launch_bounds__(256)
void gemm_qkv_rope(const ushort* __restrict__ A, const ushort* __restrict__ Bt,
                   const float* __restrict__ biasQ, const float2* __restrict__ tab,
                   ushort* __restrict__ Qf, ushort* __restrict__ Kf,
                   ushort* __restrict__ Vf)
{
  __shared__ ushort smem[9216];          // staging 6144 | QK-T 8448 | V-T 9216
  ushort* As = smem;                     // 64*32
  ushort* Bs = smem + 2048;              // 128*32
  const int bx = blockIdx.x;
  const int n0 = bx * 128;
  const int m0 = blockIdx.y * 64;
  const int t = threadIdx.x;
  const int w = t >> 6, lane = t & 63;
  const int quad = lane >> 4, nn = lane & 15;
  const int wm = (w & 1) * 32, wn = (w >> 1) * 64;

  f32x4 acc[2][4];
#pragma unroll
  for (int i = 0; i < 2; i++)
#pragma unroll
    for (int j = 0; j < 4; j++) acc[i][j] = (f32x4){0.f, 0.f, 0.f, 0.f};

  for (int k0 = 0; k0 < HID; k0 += 32) {
    __syncthreads();
#pragma unroll
    for (int c = 0; c < 3; c++) {
      int ch = w * 3 + c;
      int rr = (lane >> 2), cl = lane & 3;
      if (ch < 4) {
        int r = ch * 16 + rr;
        int cg = cl ^ ((r >> 1) & 3);
        gload16(A + (size_t)(m0 + r) * HID + k0 + cg * 8, &As[r * 32 + cl * 8]);
      } else {
        int r = (ch - 4) * 16 + rr;
        int cg = cl ^ ((r >> 1) & 3);
        gload16(Bt + (size_t)(n0 + r) * HID + k0 + cg * 8, &Bs[r * 32 + cl * 8]);
      }
    }
    __syncthreads();

    bf16x8 aF[2], bF[4];
#pragma unroll
    for (int i = 0; i < 2; i++) {
      int ra = wm + i * 16 + nn;
      aF[i] = *(const bf16x8*)(&As[ra * 32 + (quad ^ ((ra >> 1) & 3)) * 8]);
    }
#pragma unroll
    for (int j = 0; j < 4; j++) {
      int rb = wn + j * 16 + nn;
      bF[j] = *(const bf16x8*)(&Bs[rb * 32 + (quad ^ ((rb >> 1) & 3)) * 8]);
    }
#pragma unroll
    for (int i = 0; i < 2; i++)
#pragma unroll
      for (int j = 0; j < 4; j++)
        acc[i][j] = __builtin_amdgcn_mfma_f32_16x16x32_bf16(aF[i], bF[j], acc[i][j], 0, 0, 0);
  }

  float bv[4];
#pragma unroll
  for (int j = 0; j < 4; j++) bv[j] = biasQ[n0 + wn + j * 16 + nn];

  if (bx < 8) {
    // Q heads get QSCALE (bx<7 => both heads Q; bx==7 => both K). Wave-uniform.
    const float qs = (bx < 7) ? QSCALE : 1.0f;
    __syncthreads();                      // staging reads of last k-iter done
    const int ht = w >> 1;
    ushort* T = smem + ht * 4224;
#pragma unroll
    for (int i = 0; i < 2; i++) {
#pragma unroll
      for (int r = 0; r < 4; r++) {
        int row = wm + i * 16 + quad * 4 + r;
        int m = m0 + row;
        float2 cs0 = tab[m * 32 + nn];
        float2 cs1 = tab[m * 32 + 16 + nn];
        float x0 = (acc[i][0][r] + bv[0]) * qs;
        float x1 = (acc[i][1][r] + bv[1]) * qs;
        float x2 = (acc[i][2][r] + bv[2]) * qs;
        float x3 = (acc[i][3][r] + bv[3]) * qs;
        T[row * 66 + nn]      = f2bs(x0 * cs0.x - x2 * cs0.y);
        T[row * 66 + 16 + nn] = f2bs(x1 * cs1.x - x3 * cs1.y);
        T[row * 66 + 32 + nn] = f2bs(x2 * cs0.x + x0 * cs0.y);
        T[row * 66 + 48 + nn] = f2bs(x3 * cs1.x + x1 * cs1.y);
      }
    }
    __syncthreads();
    // fragment-order scatter: dst slot ((mq*4+s)*64 + hi*32 + lo)*8
    const int ht2 = t >> 7, tl = t & 127, row2 = tl >> 1, col0 = (tl & 1) * 32;
    const int m = m0 + row2, b = m >> 11, n = m & (NN - 1);
    const int hg = bx * 2 + ht2;
    const int mq = n >> 5, lo2 = n & 31;
    ushort* base = (hg < HQ)
        ? Qf + (size_t)(b * HQ + hg) * NN * DD
        : Kf + (size_t)(b * HKV + (hg - HQ)) * NN * DD;
    const ushort* src = smem + ht2 * 4224 + row2 * 66 + col0;
#pragma unroll
    for (int u = 0; u < 4; u++) {
      int d = col0 + u * 8;
      int s = d >> 4, hi2 = (d >> 3) & 1;
      *(uint4*)(base + ((size_t)(mq * 4 + s) * 64 + hi2 * 32 + lo2) * 8) =
          ((const uint4*)src)[u];
    }
  } else {
    // V: bias + transpose via LDS -> fragment-order Vf
    __syncthreads();
    const int kvh = wn >> 6;
    ushort* T = smem + kvh * (64 * 72);
#pragma unroll
    for (int j = 0; j < 4; j++) {
      int dd = j * 16 + nn;
      float bvj = bv[j];
#pragma unroll
      for (int i = 0; i < 2; i++) {
        int mloc = wm + i * 16 + quad * 4;
        ushort4 pk;
        pk.x = f2bs(acc[i][j][0] + bvj);
        pk.y = f2bs(acc[i][j][1] + bvj);
        pk.z = f2bs(acc[i][j][2] + bvj);
        pk.w = f2bs(acc[i][j][3] + bvj);
        *(ushort4*)(&T[dd * 72 + mloc]) = pk;
      }
    }
    __syncthreads();
    // thread holds V^T[dout=dd2][n = nbase..nbase+31] (one 32-key tile)
    const int head = t >> 7, dd2 = (t >> 1) & 63, seg = t & 1;
    const int b = m0 >> 11, nbase = (m0 & (NN - 1)) + seg * 32;
    const int mt = nbase >> 5;                 // 32-aligned -> single tile
    const int d2 = dd2 >> 5, lo2 = dd2 & 31;
    const ushort* src = smem + head * (64 * 72) + dd2 * 72 + seg * 32;
    ushort* base = Vf + (size_t)(b * HKV + head) * NN * DD;
#pragma unroll
    for (int u = 0; u < 4; u++) {
      int w2 = u >> 1, hi2 = u & 1;
      int g = d2 * 2 + w2;
      *(uint4*)(base + ((size_t)(mt * 4 + g) * 64 + hi2 * 32 + lo2) * 8) =
          ((const uint4*)src)[u];
    }
  }
}

// ---------------------------------------------------------------------------
// o-projection GEMM (64x128, BK=32), fp32 out — round-7 config (the 128x128
// variant measured neutral: its 3.5 waves/CU occupancy cancelled the per-wave
// gain; 448 blocks / 7 waves-per-CU wins on this small GEMM).
// ---------------------------------------------------------------------------
__global__ __launch_bounds__(256)
void gemm_o(const ushort* __restrict__ A, const ushort* __restrict__ Bt,
            float* __restrict__ out)
{
  const int n0 = blockIdx.x * 128;
  const int m0 = blockIdx.y * 64;
  __shared__ ushort As[64 * 32];
  __shared__ ushort Bs[128 * 32];
  const int t = threadIdx.x;
  const int w = t >> 6, lane = t & 63;
  const int quad = lane >> 4, nn = lane & 15;
  const int wm = (w & 1) * 32, wn = (w >> 1) * 64;

  f32x4 acc[2][4];
#pragma unroll
  for (int i = 0; i < 2; i++)
#pragma unroll
    for (int j = 0; j < 4; j++) acc[i][j] = (f32x4){0.f, 0.f, 0.f, 0.f};

  for (int k0 = 0; k0 < HID; k0 += 32) {
    __syncthreads();
#pragma unroll
    for (int c = 0; c < 3; c++) {
      int ch = w * 3 + c;
      int rr = (lane >> 2), cl = lane & 3;
      if (ch < 4) {
        int r = ch * 16 + rr;
        int cg = cl ^ ((r >> 1) & 3);
        gload16(A + (size_t)(m0 + r) * HID + k0 + cg * 8, &As[r * 32 + cl * 8]);
      } else {
        int r = (ch - 4) * 16 + rr;
        int cg = cl ^ ((r >> 1) & 3);
        gload16(Bt + (size_t)(n0 + r) * HID + k0 + cg * 8, &Bs[r * 32 + cl * 8]);
      }
    }
    __syncthreads();

    bf16x8 aF[2], bF[4];
#pragma unroll
    for (int i = 0; i < 2; i++) {
      int ra = wm + i * 16 + nn;
      aF[i] = *(const bf16x8*)(&As[ra * 32 + (quad ^ ((ra >> 1) & 3)) * 8]);
    }
#pragma unroll
    for (int j = 0; j < 4; j++) {
      int rb = wn + j * 16 + nn;
      bF[j] = *(const bf16x8*)(&Bs[rb * 32 + (quad ^ ((rb >> 1) & 3)) * 8]);
    }
#pragma unroll
    for (int i = 0; i < 2; i++)
#pragma unroll
      for (int j = 0; j < 4; j++)
        acc[i][j] = __builtin_amdgcn_mfma_f32_16x16x32_bf16(aF[i], bF[j], acc[i][j], 0, 0, 0);
  }

#pragma unroll
  for (int j = 0; j < 4; j++) {
    const int col = n0 + wn + j * 16 + nn;
#pragma unroll
    for (int i = 0; i < 2; i++) {
      const int row = m0 + wm + i * 16 + quad * 4;
#pragma unroll
      for (int r = 0; r < 4; r++)
        out[(size_t)(row + r) * HID + col] = acc[i][j][r];
    }
  }
}

// ---------------------------------------------------------------------------
// Flash attention, 32 Q-rows per wave, 32-key tiles, 32x32x16 MFMA, fully
// in-register softmax, fragment-order coalesced loads. Loop structure is
// ROUND-7 (prefetch nK/nV -> vmcnt(0) -> COPY to rK/rV; do NOT ping-pong).
// VALU diet v3 (only changes vs round 7, all inside attn_tile32):
//   * max tree reads st directly with fresh temps (-16 movs)
//   * exp2 in place on st (-16 movs)
//   * vector partial-sum accumulator ls += st (16 adds, no per-tile tree);
//     rescaled by alpha on the rare defer-rescale event; one tree in epilogue
// C/D map (m74/m101): col=lane&31, row=(reg&3)+8*(reg>>2)+4*(lane>>5).
// Defer-rescale (T13); Q pre-scaled by 0.125*log2(e) -> bare exp2f.
// ---------------------------------------------------------------------------
#define GLD(dst, ptr, offlit) \
  asm volatile("global_load_dwordx4 %0, %1, off offset:" #offlit \
               : "=v"(dst) : "v"(ptr))

__device__ __forceinline__ void issue_tile32(
    int m, int lane,
    const ushort* __restrict__ Kbf, const ushort* __restrict__ Vbf,
    u32x4 (&rK)[4], u32x4 (&rV)[4])
{
  const ushort* kp = Kbf + (size_t)m * 2048 + lane * 8;
  GLD(rK[0], kp, 0);
  GLD(rK[1], kp, 1024);
  GLD(rK[2], kp, 2048);
  GLD(rK[3], kp, 3072);
  const ushort* vp = Vbf + (size_t)m * 2048 + lane * 8;
  GLD(rV[0], vp, 0);
  GLD(rV[1], vp, 1024);
  GLD(rV[2], vp, 2048);
  GLD(rV[3], vp, 3072);
  __builtin_amdgcn_sched_barrier(0);   // pin issue point: nothing crosses
}

template <bool DIAG>
__device__ __forceinline__ void attn_tile32(
    int m, int qglob, int hi,
    const u32x4 (&rK)[4], const u32x4 (&rV)[4],
    const bf16x8 (&bQ)[4],
    f32x16 (&accO)[2], float& mst, f32x16& ls)
{
  // S^T[key][q]: lane holds q = lane&31, keys m*32 + (e&3)+8*(e>>2)+4*hi
  f32x16 st;
#pragma unroll
  for (int e = 0; e < 16; e++) st[e] = 0.f;
  __builtin_amdgcn_s_setprio(1);
#pragma unroll
  for (int s = 0; s < 4; s++)
    st = __builtin_amdgcn_mfma_f32_32x32x16_bf16(
        __builtin_bit_cast(bf16x8, rK[s]), bQ[s], st, 0, 0, 0);
  __builtin_amdgcn_s_setprio(0);

  if (DIAG) {
#pragma unroll
    for (int e = 0; e < 16; e++) {
      int key = m * 32 + (e & 3) + 8 * (e >> 2) + 4 * hi;
      if (key > qglob) st[e] = -1e30f;
    }
  }

  // row max: fresh-temp tree reading st directly + shfl cross-half
  float t8[8], t4[4];
#pragma unroll
  for (int i = 0; i < 8; i++) t8[i] = fmaxf(st[i], st[i + 8]);
#pragma unroll
  for (int i = 0; i < 4; i++) t4[i] = fmaxf(t8[i], t8[i + 4]);
  float t2a = fmaxf(t4[0], t4[2]), t2b = fmaxf(t4[1], t4[3]);
  float m16 = fmaxf(t2a, t2b);
  float mx = fmaxf(m16, __shfl_xor(m16, 32));

  if (__any(mx > mst + 8.0f)) {          // T13 defer-rescale
    float mn = fmaxf(mst, mx);
    float alpha = exp2f(mst - mn);
    mst = mn;
    ls *= alpha;
    accO[0] *= alpha;
    accO[1] *= alpha;
  }

  // P = exp2(S - m) in place; element-wise partial-sum accumulate (tree is
  // deferred to the epilogue — exact same sum, different association)
#pragma unroll
  for (int e = 0; e < 16; e++) st[e] = exp2f(st[e] - mst);
  ls += st;

  // pack + cross-half redistribute -> PV B-fragments (verified round 5)
  bf16x8 pf[2];
#pragma unroll
  for (int w = 0; w < 2; w++) {
    int e0 = w * 8;
    uint c01 = cvtpk(st[e0 + 0], st[e0 + 1]);
    uint c23 = cvtpk(st[e0 + 2], st[e0 + 3]);
    uint c45 = cvtpk(st[e0 + 4], st[e0 + 5]);
    uint c67 = cvtpk(st[e0 + 6], st[e0 + 7]);
    perm32swap(c01, c45);
    perm32swap(c23, c67);
    pf[w] = __builtin_bit_cast(bf16x8, (u32x4){c01, c23, c45, c67});
  }

  __builtin_amdgcn_s_setprio(1);
#pragma unroll
  for (int d = 0; d < 2; d++)
#pragma unroll
    for (int w = 0; w < 2; w++)
      accO[d] = __builtin_amdgcn_mfma_f32_32x32x16_bf16(
          __builtin_bit_cast(bf16x8, rV[d * 2 + w]), pf[w], accO[d], 0, 0, 0);
  __builtin_amdgcn_s_setprio(0);
}

// ---------------------------------------------------------------------------
// Barrier-free split-KV flash attention: one wave per block, 32 Q-rows.
// 32-key tiles; chunks of 28 tiles (896 keys). grid.x = 108 per (h,b):
//   u<28: qt=u, nc=1; u<84: qt=28+(v>>1), nc=2; else qt=56+v/3, nc=3.
// Bulk tiles branch-free; the diagonal tile (m=qt) runs once, masked.
// ---------------------------------------------------------------------------
__global__ __launch_bounds__(64, 3)
void attn_kernel(const ushort* __restrict__ Q, const ushort* __restrict__ K,
                 const ushort* __restrict__ Vt, ushort* __restrict__ O,
                 ushort* __restrict__ Opart, float* __restrict__ mpart,
                 float* __restrict__ lpart)
{
  const int u = 107 - (int)blockIdx.x;      // heavy blocks first
  int qt, c;
  if (u < 28)      { qt = u; c = 0; }
  else if (u < 84) { int v = u - 28; qt = 28 + (v >> 1); c = v & 1; }
  else             { int v = u - 84; qt = 56 + v / 3; c = v - (v / 3) * 3; }
  const int h = blockIdx.y, b = blockIdx.z;
  const int kvh = h / (HQ / HKV);
  const int q0 = qt * 32;
  const int nc = qt / 28 + 1;
  const int mlo = c * 28;
  const bool hasdiag = (c == nc - 1);
  const int mB = hasdiag ? qt : mlo + 28;   // bulk tile range [mlo, mB)

  const int lane = threadIdx.x;
  const int lo = lane & 31, hi = lane >> 5;
  const int qglob = q0 + lo;

  // Q fragments (fragment-order layout): coalesced lane*16B loads
  const ushort* Qf = Q + (size_t)(b * HQ + h) * NN * DD;
  bf16x8 bQ[4];
#pragma unroll
  for (int s = 0; s < 4; s++)
    bQ[s] = *(const bf16x8*)(Qf + ((size_t)(qt * 4 + s) * 64 + lane) * 8);

  const ushort* Kbf = K  + (size_t)(b * HKV + kvh) * NN * DD;
  const ushort* Vbf = Vt + (size_t)(b * HKV + kvh) * NN * DD;

  f32x16 accO[2], ls;
#pragma unroll
  for (int e = 0; e < 16; e++) { accO[0][e] = 0.f; accO[1][e] = 0.f; ls[e] = 0.f; }
  float mst = -1e30f;

  u32x4 rK[4], rV[4], nK[4], nV[4];
  issue_tile32(mlo, lane, Kbf, Vbf, rK, rV);
  asm volatile("s_waitcnt vmcnt(0)");
  __builtin_amdgcn_sched_barrier(0);

  for (int m = mlo; m < mB; m++) {
    issue_tile32(m + 1, lane, Kbf, Vbf, nK, nV);   // m+1 <= qt <= 63: valid
    attn_tile32<false>(m, qglob, hi, rK, rV, bQ, accO, mst, ls);
    asm volatile("s_waitcnt vmcnt(0)");
    __builtin_amdgcn_sched_barrier(0);
#pragma unroll
    for (int i = 0; i < 4; i++) { rK[i] = nK[i]; rV[i] = nV[i]; }
  }
  if (hasdiag)
    attn_tile32<true>(qt, qglob, hi, rK, rV, bQ, accO, mst, ls);

  // epilogue sum tree (deferred from the per-tile loop) + cross-half
  float e8[8], e4[4];
#pragma unroll
  for (int i = 0; i < 8; i++) e8[i] = ls[i] + ls[i + 8];
#pragma unroll
  for (int i = 0; i < 4; i++) e4[i] = e8[i] + e8[i + 4];
  const float lac = (e4[0] + e4[2]) + (e4[1] + e4[3]);
  const float ltot = lac + __shfl_xor(lac, 32);

  // lane holds O[q=lo][d = dtile*32 + (reg&3)+8*(reg>>2)+4*hi]
  if (nc == 1) {
    const float linv = 1.f / (ltot + 1e-8f);
    ushort* Orow = O + (size_t)(b * NN + q0 + lo) * HID + h * DD;
#pragma unroll
    for (int d = 0; d < 2; d++)
#pragma unroll
      for (int g = 0; g < 4; g++) {
        ushort4 ov;
        ov.x = f2bs(accO[d][g * 4 + 0] * linv);
        ov.y = f2bs(accO[d][g * 4 + 1] * linv);
        ov.z = f2bs(accO[d][g * 4 + 2] * linv);
        ov.w = f2bs(accO[d][g * 4 + 3] * linv);
        *(ushort4*)(Orow + d * 32 + g * 8 + 4 * hi) = ov;
      }
  } else {
    const int off = (qt < 56) ? (qt - 28) * 2 : 56 + (qt - 56) * 3;
    const int p = (b * HQ + h) * 80 + off + c;
    ushort* Op = Opart + (size_t)p * 2048 + lo * 64;
#pragma unroll
    for (int d = 0; d < 2; d++)
#pragma unroll
      for (int g = 0; g < 4; g++) {
        ushort4 ov;
        ov.x = f2bs(accO[d][g * 4 + 0]);
        ov.y = f2bs(accO[d][g * 4 + 1]);
        ov.z = f2bs(accO[d][g * 4 + 2]);
        ov.w = f2bs(accO[d][g * 4 + 3]);
        *(ushort4*)(Op + d * 32 + g * 8 + 4 * hi) = ov;
      }
    if (hi == 0) {
      mpart[(size_t)p * 32 + lo] = mst;   // log2 units
      lpart[(size_t)p * 32 + lo] = ltot;
    }
  }
}

// ---------------------------------------------------------------------------
// Reduce: merge 2-3 chunk partials for qt 28..63. grid (36, 14, 2), 256 thr.
// ---------------------------------------------------------------------------
__global__ __launch_bounds__(256)
void attn_reduce_kernel(const ushort* __restrict__ Opart, const float* __restrict__ mpart,
                        const float* __restrict__ lpart, ushort* __restrict__ O)
{
  const int qt = 28 + blockIdx.x;
  const int h = blockIdx.y, b = blockIdx.z;
  const int nc = (qt < 56) ? 2 : 3;
  const int off = (qt < 56) ? (qt - 28) * 2 : 56 + (qt - 56) * 3;
  const int pb = (b * HQ + h) * 80 + off;
  const int t = threadIdx.x;
  const int row = t >> 3, seg = t & 7;

  float mv[3], lv[3];
  float M = -1e30f;
  for (int c = 0; c < nc; c++) {
    mv[c] = mpart[(size_t)(pb + c) * 32 + row];
    lv[c] = lpart[(size_t)(pb + c) * 32 + row];
    M = fmaxf(M, mv[c]);
  }
  float l = 0.f, wv[3];
  for (int c = 0; c < nc; c++) { wv[c] = exp2f(mv[c] - M); l += lv[c] * wv[c]; }
  const float linv = 1.f / (l + 1e-8f);

  float av[8];
#pragma unroll
  for (int k = 0; k < 8; k++) av[k] = 0.f;
  for (int c = 0; c < nc; c++) {
    const ushort* Op = Opart + (size_t)(pb + c) * 2048 + row * 64 + seg * 8;
#pragma unroll
    for (int k = 0; k < 8; k++) av[k] += wv[c] * bs2f(Op[k]);
  }
  ushort ov[8];
#pragma unroll
  for (int k = 0; k < 8; k++) ov[k] = f2bs(av[k] * linv);
  ushort* Od = O + (size_t)(b * NN + qt * 32 + row) * HID + h * DD + seg * 8;
  *(uint4*)Od = *(uint4*)ov;
}

// ---------------------------------------------------------------------------
extern "C" void kernel_launch(void* const* d_in, const int* in_sizes, int n_in,
                              void* d_out, int out_size, void* d_ws, size_t ws_size,
                              hipStream_t stream)
{
  const float* hid = (const float*)d_in[0];
  const int*   pos = (const int*)  d_in[1];
  const float* qw  = (const float*)d_in[2];
  const float* qb  = (const float*)d_in[3];
  const float* kw  = (const float*)d_in[4];
  const float* kb  = (const float*)d_in[5];
  const float* vw  = (const float*)d_in[6];
  const float* vb  = (const float*)d_in[7];
  const float* ow  = (const float*)d_in[8];
  float* outp = (float*)d_out;

  // ws (ushort units). WoT first so WqkvT+Ah form a contiguous dead region for
  // Opart (2240 slots x 2048 = 4,587,520 <= 4,702,208).
  ushort* WoT   = (ushort*)d_ws;                          //   802,816
  ushort* WqkvT = WoT   + (size_t)HID * HID;              // 1,032,192
  ushort* Ah    = WqkvT + (size_t)QKV_COLS * HID;         // 3,670,016
  ushort* Qb    = Ah    + (size_t)4096 * HID;             // 3,670,016
  ushort* Kb    = Qb    + (size_t)BB * HQ  * NN * DD;     //   524,288
  ushort* Vtb   = Kb    + (size_t)BB * HKV * NN * DD;     //   524,288
  ushort* Ob    = Vtb   + (size_t)BB * HKV * NN * DD;     // 3,670,016
  float2* tab   = (float2*)(Ob + (size_t)4096 * HID);     // 4096*32 float2
  float*  biasQ = (float*)(tab + (size_t)4096 * 32);      // 1152
  float*  mpart = biasQ + QKV_COLS;                       // 2240*32 = 71,680
  float*  lpart = mpart + (size_t)2240 * 32;
  ushort* Opart = WqkvT;                                  // overlay (dead region)

  prep_kernel<<<dim3(5893), 256, 0, stream>>>(hid, pos, qw, kw, vw, ow, qb, kb, vb,
                                              Ah, WqkvT, WoT, tab, biasQ);
  gemm_qkv_rope<<<dim3(9, 64), 256, 0, stream>>>(Ah, WqkvT, biasQ, tab, Qb, Kb, Vtb);
  attn_kernel<<<dim3(108, HQ, BB), 64, 0, stream>>>(Qb, Kb, Vtb, Ob, Opart, mpart, lpart);
  attn_reduce_kernel<<<dim3(36, HQ, BB), 256, 0, stream>>>(Opart, mpart, lpart, Ob);
  gemm_o<<<dim3(HID / 128, 64), 256, 0, stream>>>(Ob, WoT, outp);
}

// Round 12
// 177.719 us; speedup vs baseline: 1.1525x; 1.1525x over previous
//
#include <hip/hip_runtime.h>
#include <math.h>

#define BB 2
#define NN 2048
#define HID 896
#define HQ 14
#define HKV 2
#define DD 64
#define QKV_COLS 1152
#define QSCALE 0.18033688011112042f   // 0.125 * log2(e), folded into Q

typedef __bf16 bf16x8 __attribute__((ext_vector_type(8)));
typedef float f32x4 __attribute__((ext_vector_type(4)));
typedef float f32x16 __attribute__((ext_vector_type(16)));
typedef uint u32x4 __attribute__((ext_vector_type(4)));

__device__ inline ushort f2bs(float f) {   // fp32 -> bf16 (RNE), finite inputs
  uint u = __builtin_bit_cast(uint, f);
  u += 0x7FFFu + ((u >> 16) & 1u);
  return (ushort)(u >> 16);
}
__device__ inline float bs2f(ushort u) {
  return __builtin_bit_cast(float, (uint)u << 16);
}

__device__ inline void gload16(const ushort* g, ushort* l) {
  __builtin_amdgcn_global_load_lds(
      (const __attribute__((address_space(1))) uint*)g,
      (__attribute__((address_space(3))) uint*)l, 16, 0, 0);
}

// packed f32x2 -> bf16x2 (RNE), single VALU op
__device__ inline uint cvtpk(float lo, float hi) {
  uint d;
  asm("v_cvt_pk_bf16_f32 %0, %1, %2" : "=v"(d) : "v"(lo), "v"(hi));
  return d;
}
// v_permlane32_swap_b32 vdst, vsrc:
//   new vdst[32:63] = old vsrc[0:31]; new vsrc[0:31] = old vdst[32:63]
__device__ inline void perm32swap(uint& a, uint& b) {
  asm("v_permlane32_swap_b32 %0, %1" : "+v"(a), "+v"(b));
}

// ---------------------------------------------------------------------------
// Fragment-order layouts (verified round 7): Q/K as [head][tile m][s][lane][8]
// where lane = hi*32+lo holds X[n = m*32+lo][d = s*16+hi*8+e]. V as
// [head][tile m][g][lane][8], g = d*2+w, lane holds V^T[dout = d*32+lo]
// [n = m*32 + w*16 + hi*8 + e]. Attn loads: base + lane*16B, 4KB/tile.
//
// FROZEN (rounds 8-11 lessons): attn inner loop is the round-7 shape —
// prefetch into nK/nV, vmcnt(0), COPY to rK/rV, compute with red[16]/p[16]
// temps. Ping-pong (r8/r9) corrupted K/V via allocator aliasing of in-flight
// asm outputs; the ls-vector accumulator (r11) spilled (+12MB WRITE, +18us).
// The tile body is at a register-pressure equilibrium: do not touch it.
// ---------------------------------------------------------------------------

// ---------------------------------------------------------------------------
// prep: [0,3584) cast hidden->bf16 | [3584,4592) qkv-w pack | [4592,5376) o-w
// pack | [5376,5888) rope cos/sin table | [5888,5893) bias pack
// ---------------------------------------------------------------------------
__global__ __launch_bounds__(256)
void prep_kernel(const float* __restrict__ hid, const int* __restrict__ pos,
                 const float* __restrict__ qw, const float* __restrict__ kw,
                 const float* __restrict__ vw, const float* __restrict__ ow,
                 const float* __restrict__ qb, const float* __restrict__ kb,
                 const float* __restrict__ vb,
                 ushort* __restrict__ Ah, ushort* __restrict__ WqkvT,
                 ushort* __restrict__ WoT, float2* __restrict__ tab,
                 float* __restrict__ biasQ)
{
  __shared__ float tile[32][33];
  const int blk = blockIdx.x, t = threadIdx.x;
  if (blk < 3584) {
    int i = blk * 256 + t;
    float4 v = ((const float4*)hid)[i];
    ushort4 o;
    o.x = f2bs(v.x); o.y = f2bs(v.y); o.z = f2bs(v.z); o.w = f2bs(v.w);
    ((ushort4*)Ah)[i] = o;
  } else if (blk < 5376) {
    const float* src; int N, n0, drow, k0;
    if (blk < 4592) {
      int idx = blk - 3584;
      int bx = idx % 36; k0 = (idx / 36) * 32;
      if (bx < 28)      { src = qw; N = 896; n0 = bx * 32;        drow = n0; }
      else if (bx < 32) { src = kw; N = 128; n0 = (bx - 28) * 32; drow = 896 + n0; }
      else              { src = vw; N = 128; n0 = (bx - 32) * 32; drow = 1024 + n0; }
    } else {
      int idx = blk - 4592;
      src = ow; N = 896; n0 = (idx % 28) * 32; k0 = (idx / 28) * 32; drow = n0;
    }
    ushort* dst = (blk < 4592) ? WqkvT : WoT;
    const int tx = t & 31, ty = t >> 5;
#pragma unroll
    for (int i = 0; i < 32; i += 8)
      tile[ty + i][tx] = src[(size_t)(k0 + ty + i) * N + n0 + tx];
    __syncthreads();
#pragma unroll
    for (int i = 0; i < 32; i += 8)
      dst[(size_t)(drow + ty + i) * HID + k0 + tx] = f2bs(tile[tx][ty + i]);
  } else if (blk < 5888) {
    int idx = (blk - 5376) * 256 + t;     // 0 .. 131071
    int m = idx >> 5, f = idx & 31;
    float inv = exp2f(-(float)f * (19.9315685693241741f / 32.0f));
    float ang = (float)pos[m] * inv;
    float sv, cv;
    sincosf(ang, &sv, &cv);
    tab[idx] = make_float2(cv, sv);
  } else {
    int i = (blk - 5888) * 256 + t;
    if (i < QKV_COLS)
      biasQ[i] = (i < 896) ? qb[i] : (i < 1024 ? kb[i - 896] : vb[i - 1024]);
  }
}

// ---------------------------------------------------------------------------
// QKV GEMM — BK=64 as TWO side-by-side copies of the verified BK=32 panel:
// four LDS panels As0/As1/Bs0/Bs1, each in the exact round-7 layout (row*32 +
// swizzled 8-col groups; gload16 dest = wave-uniform base + lane*16B within
// each panel). 14 staging/barrier rounds instead of 28; 32 MFMA per round.
// Fused bias + RoPE + fragment-order scatter epilogue unchanged.
// grid (9, 64).
// ---------------------------------------------------------------------------
__global__ __launch_bounds__(256)
void gemm_qkv_rope(const ushort* __restrict__ A, const ushort* __restrict__ Bt,
                   const float* __restrict__ biasQ, const float2* __restrict__ tab,
                   ushort* __restrict__ Qf, ushort* __restrict__ Kf,
                   ushort* __restrict__ Vf)
{
  __shared__ ushort smem[12288];   // As0 2048 | As1 2048 | Bs0 4096 | Bs1 4096
                                   // epilogue reuse: QK-T 8448 | V-T 9216
  const int bx = blockIdx.x;
  const int n0 = bx * 128;
  const int m0 = blockIdx.y * 64;
  const int t = threadIdx.x;
  const int w = t >> 6, lane = t & 63;
  const int quad = lane >> 4, nn = lane & 15;
  const int wm = (w & 1) * 32, wn = (w >> 1) * 64;

  f32x4 acc[2][4];
#pragma unroll
  for (int i = 0; i < 2; i++)
#pragma unroll
    for (int j = 0; j < 4; j++) acc[i][j] = (f32x4){0.f, 0.f, 0.f, 0.f};

  for (int k0 = 0; k0 < HID; k0 += 64) {
    __syncthreads();
#pragma unroll
    for (int c = 0; c < 6; c++) {
      int ch = w * 6 + c;                  // 24 channels: 8 A-panels, 16 B-panels
      int rr = lane >> 2, cl = lane & 3;
      if (ch < 8) {
        int half = ch >> 2;                // 0 -> As0, 1 -> As1
        int r = (ch & 3) * 16 + rr;
        int cg = cl ^ ((r >> 1) & 3);
        gload16(A + (size_t)(m0 + r) * HID + k0 + half * 32 + cg * 8,
                &smem[half * 2048 + r * 32 + cl * 8]);
      } else {
        int ch2 = ch - 8;                  // 0..15
        int half = ch2 >> 3;               // 0 -> Bs0, 1 -> Bs1
        int r = (ch2 & 7) * 16 + rr;
        int cg = cl ^ ((r >> 1) & 3);
        gload16(Bt + (size_t)(n0 + r) * HID + k0 + half * 32 + cg * 8,
                &smem[4096 + half * 4096 + r * 32 + cl * 8]);
      }
    }
    __syncthreads();

#pragma unroll
    for (int kh = 0; kh < 2; kh++) {
      const ushort* Ap = smem + kh * 2048;
      const ushort* Bp = smem + 4096 + kh * 4096;
      bf16x8 aF[2], bF[4];
#pragma unroll
      for (int i = 0; i < 2; i++) {
        int ra = wm + i * 16 + nn;
        aF[i] = *(const bf16x8*)(&Ap[ra * 32 + (quad ^ ((ra >> 1) & 3)) * 8]);
      }
#pragma unroll
      for (int j = 0; j < 4; j++) {
        int rb = wn + j * 16 + nn;
        bF[j] = *(const bf16x8*)(&Bp[rb * 32 + (quad ^ ((rb >> 1) & 3)) * 8]);
      }
#pragma unroll
      for (int i = 0; i < 2; i++)
#pragma unroll
        for (int j = 0; j < 4; j++)
          acc[i][j] = __builtin_amdgcn_mfma_f32_16x16x32_bf16(aF[i], bF[j], acc[i][j], 0, 0, 0);
    }
  }

  float bv[4];
#pragma unroll
  for (int j = 0; j < 4; j++) bv[j] = biasQ[n0 + wn + j * 16 + nn];

  if (bx < 8) {
    // Q heads get QSCALE (bx<7 => both heads Q; bx==7 => both K). Wave-uniform.
    const float qs = (bx < 7) ? QSCALE : 1.0f;
    __syncthreads();                      // staging reads of last k-iter done
    const int ht = w >> 1;
    ushort* T = smem + ht * 4224;
#pragma unroll
    for (int i = 0; i < 2; i++) {
#pragma unroll
      for (int r = 0; r < 4; r++) {
        int row = wm + i * 16 + quad * 4 + r;
        int m = m0 + row;
        float2 cs0 = tab[m * 32 + nn];
        float2 cs1 = tab[m * 32 + 16 + nn];
        float x0 = (acc[i][0][r] + bv[0]) * qs;
        float x1 = (acc[i][1][r] + bv[1]) * qs;
        float x2 = (acc[i][2][r] + bv[2]) * qs;
        float x3 = (acc[i][3][r] + bv[3]) * qs;
        T[row * 66 + nn]      = f2bs(x0 * cs0.x - x2 * cs0.y);
        T[row * 66 + 16 + nn] = f2bs(x1 * cs1.x - x3 * cs1.y);
        T[row * 66 + 32 + nn] = f2bs(x2 * cs0.x + x0 * cs0.y);
        T[row * 66 + 48 + nn] = f2bs(x3 * cs1.x + x1 * cs1.y);
      }
    }
    __syncthreads();
    // fragment-order scatter: dst slot ((mq*4+s)*64 + hi*32 + lo)*8
    const int ht2 = t >> 7, tl = t & 127, row2 = tl >> 1, col0 = (tl & 1) * 32;
    const int m = m0 + row2, b = m >> 11, n = m & (NN - 1);
    const int hg = bx * 2 + ht2;
    const int mq = n >> 5, lo2 = n & 31;
    ushort* base = (hg < HQ)
        ? Qf + (size_t)(b * HQ + hg) * NN * DD
        : Kf + (size_t)(b * HKV + (hg - HQ)) * NN * DD;
    const ushort* src = smem + ht2 * 4224 + row2 * 66 + col0;
#pragma unroll
    for (int u = 0; u < 4; u++) {
      int d = col0 + u * 8;
      int s = d >> 4, hi2 = (d >> 3) & 1;
      *(uint4*)(base + ((size_t)(mq * 4 + s) * 64 + hi2 * 32 + lo2) * 8) =
          ((const uint4*)src)[u];
    }
  } else {
    // V: bias + transpose via LDS -> fragment-order Vf
    __syncthreads();
    const int kvh = wn >> 6;
    ushort* T = smem + kvh * (64 * 72);
#pragma unroll
    for (int j = 0; j < 4; j++) {
      int dd = j * 16 + nn;
      float bvj = bv[j];
#pragma unroll
      for (int i = 0; i < 2; i++) {
        int mloc = wm + i * 16 + quad * 4;
        ushort4 pk;
        pk.x = f2bs(acc[i][j][0] + bvj);
        pk.y = f2bs(acc[i][j][1] + bvj);
        pk.z = f2bs(acc[i][j][2] + bvj);
        pk.w = f2bs(acc[i][j][3] + bvj);
        *(ushort4*)(&T[dd * 72 + mloc]) = pk;
      }
    }
    __syncthreads();
    // thread holds V^T[dout=dd2][n = nbase..nbase+31] (one 32-key tile)
    const int head = t >> 7, dd2 = (t >> 1) & 63, seg = t & 1;
    const int b = m0 >> 11, nbase = (m0 & (NN - 1)) + seg * 32;
    const int mt = nbase >> 5;                 // 32-aligned -> single tile
    const int d2 = dd2 >> 5, lo2 = dd2 & 31;
    const ushort* src = smem + head * (64 * 72) + dd2 * 72 + seg * 32;
    ushort* base = Vf + (size_t)(b * HKV + head) * NN * DD;
#pragma unroll
    for (int u = 0; u < 4; u++) {
      int w2 = u >> 1, hi2 = u & 1;
      int g = d2 * 2 + w2;
      *(uint4*)(base + ((size_t)(mt * 4 + g) * 64 + hi2 * 32 + lo2) * 8) =
          ((const uint4*)src)[u];
    }
  }
}

// ---------------------------------------------------------------------------
// o-projection GEMM (64x128 tile), BK=64 via the same four-panel scheme.
// grid (7, 64), fp32 out.
// ---------------------------------------------------------------------------
__global__ __launch_bounds__(256)
void gemm_o(const ushort* __restrict__ A, const ushort* __restrict__ Bt,
            float* __restrict__ out)
{
  const int n0 = blockIdx.x * 128;
  const int m0 = blockIdx.y * 64;
  __shared__ ushort smem[12288];   // As0 | As1 | Bs0 | Bs1
  const int t = threadIdx.x;
  const int w = t >> 6, lane = t & 63;
  const int quad = lane >> 4, nn = lane & 15;
  const int wm = (w & 1) * 32, wn = (w >> 1) * 64;

  f32x4 acc[2][4];
#pragma unroll
  for (int i = 0; i < 2; i++)
#pragma unroll
    for (int j = 0; j < 4; j++) acc[i][j] = (f32x4){0.f, 0.f, 0.f, 0.f};

  for (int k0 = 0; k0 < HID; k0 += 64) {
    __syncthreads();
#pragma unroll
    for (int c = 0; c < 6; c++) {
      int ch = w * 6 + c;
      int rr = lane >> 2, cl = lane & 3;
      if (ch < 8) {
        int half = ch >> 2;
        int r = (ch & 3) * 16 + rr;
        int cg = cl ^ ((r >> 1) & 3);
        gload16(A + (size_t)(m0 + r) * HID + k0 + half * 32 + cg * 8,
                &smem[half * 2048 + r * 32 + cl * 8]);
      } else {
        int ch2 = ch - 8;
        int half = ch2 >> 3;
        int r = (ch2 & 7) * 16 + rr;
        int cg = cl ^ ((r >> 1) & 3);
        gload16(Bt + (size_t)(n0 + r) * HID + k0 + half * 32 + cg * 8,
                &smem[4096 + half * 4096 + r * 32 + cl * 8]);
      }
    }
    __syncthreads();

#pragma unroll
    for (int kh = 0; kh < 2; kh++) {
      const ushort* Ap = smem + kh * 2048;
      const ushort* Bp = smem + 4096 + kh * 4096;
      bf16x8 aF[2], bF[4];
#pragma unroll
      for (int i = 0; i < 2; i++) {
        int ra = wm + i * 16 + nn;
        aF[i] = *(const bf16x8*)(&Ap[ra * 32 + (quad ^ ((ra >> 1) & 3)) * 8]);
      }
#pragma unroll
      for (int j = 0; j < 4; j++) {
        int rb = wn + j * 16 + nn;
        bF[j] = *(const bf16x8*)(&Bp[rb * 32 + (quad ^ ((rb >> 1) & 3)) * 8]);
      }
#pragma unroll
      for (int i = 0; i < 2; i++)
#pragma unroll
        for (int j = 0; j < 4; j++)
          acc[i][j] = __builtin_amdgcn_mfma_f32_16x16x32_bf16(aF[i], bF[j], acc[i][j], 0, 0, 0);
    }
  }

#pragma unroll
  for (int j = 0; j < 4; j++) {
    const int col = n0 + wn + j * 16 + nn;
#pragma unroll
    for (int i = 0; i < 2; i++) {
      const int row = m0 + wm + i * 16 + quad * 4;
#pragma unroll
      for (int r = 0; r < 4; r++)
        out[(size_t)(row + r) * HID + col] = acc[i][j][r];
    }
  }
}

// ---------------------------------------------------------------------------
// Flash attention, 32 Q-rows per wave, 32-key tiles, 32x32x16 MFMA, fully
// in-register softmax, fragment-order coalesced loads. ROUND-7 VERBATIM
// (verified passing at 55us; FROZEN — see layout note above).
// C/D map (m74/m101): col=lane&31, row=(reg&3)+8*(reg>>2)+4*(lane>>5).
// Defer-rescale (T13); Q pre-scaled by 0.125*log2(e) -> bare exp2f.
// ---------------------------------------------------------------------------
#define GLD(dst, ptr, offlit) \
  asm volatile("global_load_dwordx4 %0, %1, off offset:" #offlit \
               : "=v"(dst) : "v"(ptr))

__device__ __forceinline__ void issue_tile32(
    int m, int lane,
    const ushort* __restrict__ Kbf, const ushort* __restrict__ Vbf,
    u32x4 (&rK)[4], u32x4 (&rV)[4])
{
  const ushort* kp = Kbf + (size_t)m * 2048 + lane * 8;
  GLD(rK[0], kp, 0);
  GLD(rK[1], kp, 1024);
  GLD(rK[2], kp, 2048);
  GLD(rK[3], kp, 3072);
  const ushort* vp = Vbf + (size_t)m * 2048 + lane * 8;
  GLD(rV[0], vp, 0);
  GLD(rV[1], vp, 1024);
  GLD(rV[2], vp, 2048);
  GLD(rV[3], vp, 3072);
  __builtin_amdgcn_sched_barrier(0);   // pin issue point: nothing crosses
}

template <bool DIAG>
__device__ __forceinline__ void attn_tile32(
    int m, int qglob, int hi,
    const u32x4 (&rK)[4], const u32x4 (&rV)[4],
    const bf16x8 (&bQ)[4],
    f32x16 (&accO)[2], float& mst, float& lac)
{
  // S^T[key][q]: lane holds q = lane&31, keys m*32 + (e&3)+8*(e>>2)+4*hi
  f32x16 st;
#pragma unroll
  for (int e = 0; e < 16; e++) st[e] = 0.f;
  __builtin_amdgcn_s_setprio(1);
#pragma unroll
  for (int s = 0; s < 4; s++)
    st = __builtin_amdgcn_mfma_f32_32x32x16_bf16(
        __builtin_bit_cast(bf16x8, rK[s]), bQ[s], st, 0, 0, 0);
  __builtin_amdgcn_s_setprio(0);

  if (DIAG) {
#pragma unroll
    for (int e = 0; e < 16; e++) {
      int key = m * 32 + (e & 3) + 8 * (e >> 2) + 4 * hi;
      if (key > qglob) st[e] = -1e30f;
    }
  }

  // row max: in-lane tree over 16 + one cross-half exchange
  float red[16];
#pragma unroll
  for (int e = 0; e < 16; e++) red[e] = st[e];
#pragma unroll
  for (int off = 8; off > 0; off >>= 1)
#pragma unroll
    for (int i = 0; i < off; i++) red[i] = fmaxf(red[i], red[i + off]);
  float mx = fmaxf(red[0], __shfl_xor(red[0], 32));

  if (__any(mx > mst + 8.0f)) {          // T13 defer-rescale
    float mn = fmaxf(mst, mx);
    float alpha = exp2f(mst - mn);
    mst = mn;
    lac *= alpha;
    accO[0] *= alpha;
    accO[1] *= alpha;
  }

  f32x16 p;
  float sred[16];
#pragma unroll
  for (int e = 0; e < 16; e++) { p[e] = exp2f(st[e] - mst); sred[e] = p[e]; }
#pragma unroll
  for (int off = 8; off > 0; off >>= 1)
#pragma unroll
    for (int i = 0; i < off; i++) sred[i] += sred[i + off];
  lac += sred[0];

  // pack + cross-half redistribute -> PV B-fragments (verified round 5)
  bf16x8 pf[2];
#pragma unroll
  for (int w = 0; w < 2; w++) {
    int e0 = w * 8;
    uint c01 = cvtpk(p[e0 + 0], p[e0 + 1]);
    uint c23 = cvtpk(p[e0 + 2], p[e0 + 3]);
    uint c45 = cvtpk(p[e0 + 4], p[e0 + 5]);
    uint c67 = cvtpk(p[e0 + 6], p[e0 + 7]);
    perm32swap(c01, c45);
    perm32swap(c23, c67);
    pf[w] = __builtin_bit_cast(bf16x8, (u32x4){c01, c23, c45, c67});
  }

  __builtin_amdgcn_s_setprio(1);
#pragma unroll
  for (int d = 0; d < 2; d++)
#pragma unroll
    for (int w = 0; w < 2; w++)
      accO[d] = __builtin_amdgcn_mfma_f32_32x32x16_bf16(
          __builtin_bit_cast(bf16x8, rV[d * 2 + w]), pf[w], accO[d], 0, 0, 0);
  __builtin_amdgcn_s_setprio(0);
}

// ---------------------------------------------------------------------------
// Barrier-free split-KV flash attention: one wave per block, 32 Q-rows.
// 32-key tiles; chunks of 28 tiles (896 keys). grid.x = 108 per (h,b):
//   u<28: qt=u, nc=1; u<84: qt=28+(v>>1), nc=2; else qt=56+v/3, nc=3.
// Bulk tiles branch-free; the diagonal tile (m=qt) runs once, masked.
// ---------------------------------------------------------------------------
__global__ __launch_bounds__(64, 3)
void attn_kernel(const ushort* __restrict__ Q, const ushort* __restrict__ K,
                 const ushort* __restrict__ Vt, ushort* __restrict__ O,
                 ushort* __restrict__ Opart, float* __restrict__ mpart,
                 float* __restrict__ lpart)
{
  const int u = 107 - (int)blockIdx.x;      // heavy blocks first
  int qt, c;
  if (u < 28)      { qt = u; c = 0; }
  else if (u < 84) { int v = u - 28; qt = 28 + (v >> 1); c = v & 1; }
  else             { int v = u - 84; qt = 56 + v / 3; c = v - (v / 3) * 3; }
  const int h = blockIdx.y, b = blockIdx.z;
  const int kvh = h / (HQ / HKV);
  const int q0 = qt * 32;
  const int nc = qt / 28 + 1;
  const int mlo = c * 28;
  const bool hasdiag = (c == nc - 1);
  const int mB = hasdiag ? qt : mlo + 28;   // bulk tile range [mlo, mB)

  const int lane = threadIdx.x;
  const int lo = lane & 31, hi = lane >> 5;
  const int qglob = q0 + lo;

  // Q fragments (fragment-order layout): coalesced lane*16B loads
  const ushort* Qf = Q + (size_t)(b * HQ + h) * NN * DD;
  bf16x8 bQ[4];
#pragma unroll
  for (int s = 0; s < 4; s++)
    bQ[s] = *(const bf16x8*)(Qf + ((size_t)(qt * 4 + s) * 64 + lane) * 8);

  const ushort* Kbf = K  + (size_t)(b * HKV + kvh) * NN * DD;
  const ushort* Vbf = Vt + (size_t)(b * HKV + kvh) * NN * DD;

  f32x16 accO[2];
#pragma unroll
  for (int d = 0; d < 2; d++)
#pragma unroll
    for (int e = 0; e < 16; e++) accO[d][e] = 0.f;
  float mst = -1e30f, lac = 0.f;

  u32x4 rK[4], rV[4], nK[4], nV[4];
  issue_tile32(mlo, lane, Kbf, Vbf, rK, rV);
  asm volatile("s_waitcnt vmcnt(0)");
  __builtin_amdgcn_sched_barrier(0);

  for (int m = mlo; m < mB; m++) {
    issue_tile32(m + 1, lane, Kbf, Vbf, nK, nV);   // m+1 <= qt <= 63: valid
    attn_tile32<false>(m, qglob, hi, rK, rV, bQ, accO, mst, lac);
    asm volatile("s_waitcnt vmcnt(0)");
    __builtin_amdgcn_sched_barrier(0);
#pragma unroll
    for (int i = 0; i < 4; i++) { rK[i] = nK[i]; rV[i] = nV[i]; }
  }
  if (hasdiag)
    attn_tile32<true>(qt, qglob, hi, rK, rV, bQ, accO, mst, lac);

  const float ltot = lac + __shfl_xor(lac, 32);

  // lane holds O[q=lo][d = dtile*32 + (reg&3)+8*(reg>>2)+4*hi]
  if (nc == 1) {
    const float linv = 1.f / (ltot + 1e-8f);
    ushort* Orow = O + (size_t)(b * NN + q0 + lo) * HID + h * DD;
#pragma unroll
    for (int d = 0; d < 2; d++)
#pragma unroll
      for (int g = 0; g < 4; g++) {
        ushort4 ov;
        ov.x = f2bs(accO[d][g * 4 + 0] * linv);
        ov.y = f2bs(accO[d][g * 4 + 1] * linv);
        ov.z = f2bs(accO[d][g * 4 + 2] * linv);
        ov.w = f2bs(accO[d][g * 4 + 3] * linv);
        *(ushort4*)(Orow + d * 32 + g * 8 + 4 * hi) = ov;
      }
  } else {
    const int off = (qt < 56) ? (qt - 28) * 2 : 56 + (qt - 56) * 3;
    const int p = (b * HQ + h) * 80 + off + c;
    ushort* Op = Opart + (size_t)p * 2048 + lo * 64;
#pragma unroll
    for (int d = 0; d < 2; d++)
#pragma unroll
      for (int g = 0; g < 4; g++) {
        ushort4 ov;
        ov.x = f2bs(accO[d][g * 4 + 0]);
        ov.y = f2bs(accO[d][g * 4 + 1]);
        ov.z = f2bs(accO[d][g * 4 + 2]);
        ov.w = f2bs(accO[d][g * 4 + 3]);
        *(ushort4*)(Op + d * 32 + g * 8 + 4 * hi) = ov;
      }
    if (hi == 0) {
      mpart[(size_t)p * 32 + lo] = mst;   // log2 units
      lpart[(size_t)p * 32 + lo] = ltot;
    }
  }
}

// ---------------------------------------------------------------------------
// Reduce: merge 2-3 chunk partials for qt 28..63. grid (36, 14, 2), 256 thr.
// ---------------------------------------------------------------------------
__global__ __launch_bounds__(256)
void attn_reduce_kernel(const ushort* __restrict__ Opart, const float* __restrict__ mpart,
                        const float* __restrict__ lpart, ushort* __restrict__ O)
{
  const int qt = 28 + blockIdx.x;
  const int h = blockIdx.y, b = blockIdx.z;
  const int nc = (qt < 56) ? 2 : 3;
  const int off = (qt < 56) ? (qt - 28) * 2 : 56 + (qt - 56) * 3;
  const int pb = (b * HQ + h) * 80 + off;
  const int t = threadIdx.x;
  const int row = t >> 3, seg = t & 7;

  float mv[3], lv[3];
  float M = -1e30f;
  for (int c = 0; c < nc; c++) {
    mv[c] = mpart[(size_t)(pb + c) * 32 + row];
    lv[c] = lpart[(size_t)(pb + c) * 32 + row];
    M = fmaxf(M, mv[c]);
  }
  float l = 0.f, wv[3];
  for (int c = 0; c < nc; c++) { wv[c] = exp2f(mv[c] - M); l += lv[c] * wv[c]; }
  const float linv = 1.f / (l + 1e-8f);

  float av[8];
#pragma unroll
  for (int k = 0; k < 8; k++) av[k] = 0.f;
  for (int c = 0; c < nc; c++) {
    const ushort* Op = Opart + (size_t)(pb + c) * 2048 + row * 64 + seg * 8;
#pragma unroll
    for (int k = 0; k < 8; k++) av[k] += wv[c] * bs2f(Op[k]);
  }
  ushort ov[8];
#pragma unroll
  for (int k = 0; k < 8; k++) ov[k] = f2bs(av[k] * linv);
  ushort* Od = O + (size_t)(b * NN + qt * 32 + row) * HID + h * DD + seg * 8;
  *(uint4*)Od = *(uint4*)ov;
}

// ---------------------------------------------------------------------------
extern "C" void kernel_launch(void* const* d_in, const int* in_sizes, int n_in,
                              void* d_out, int out_size, void* d_ws, size_t ws_size,
                              hipStream_t stream)
{
  const float* hid = (const float*)d_in[0];
  const int*   pos = (const int*)  d_in[1];
  const float* qw  = (const float*)d_in[2];
  const float* qb  = (const float*)d_in[3];
  const float* kw  = (const float*)d_in[4];
  const float* kb  = (const float*)d_in[5];
  const float* vw  = (const float*)d_in[6];
  const float* vb  = (const float*)d_in[7];
  const float* ow  = (const float*)d_in[8];
  float* outp = (float*)d_out;

  // ws (ushort units). WoT first so WqkvT+Ah form a contiguous dead region for
  // Opart (2240 slots x 2048 = 4,587,520 <= 4,702,208).
  ushort* WoT   = (ushort*)d_ws;                          //   802,816
  ushort* WqkvT = WoT   + (size_t)HID * HID;              // 1,032,192
  ushort* Ah    = WqkvT + (size_t)QKV_COLS * HID;         // 3,670,016
  ushort* Qb    = Ah    + (size_t)4096 * HID;             // 3,670,016
  ushort* Kb    = Qb    + (size_t)BB * HQ  * NN * DD;     //   524,288
  ushort* Vtb   = Kb    + (size_t)BB * HKV * NN * DD;     //   524,288
  ushort* Ob    = Vtb   + (size_t)BB * HKV * NN * DD;     // 3,670,016
  float2* tab   = (float2*)(Ob + (size_t)4096 * HID);     // 4096*32 float2
  float*  biasQ = (float*)(tab + (size_t)4096 * 32);      // 1152
  float*  mpart = biasQ + QKV_COLS;                       // 2240*32 = 71,680
  float*  lpart = mpart + (size_t)2240 * 32;
  ushort* Opart = WqkvT;                                  // overlay (dead region)

  prep_kernel<<<dim3(5893), 256, 0, stream>>>(hid, pos, qw, kw, vw, ow, qb, kb, vb,
                                              Ah, WqkvT, WoT, tab, biasQ);
  gemm_qkv_rope<<<dim3(9, 64), 256, 0, stream>>>(Ah, WqkvT, biasQ, tab, Qb, Kb, Vtb);
  attn_kernel<<<dim3(108, HQ, BB), 64, 0, stream>>>(Qb, Kb, Vtb, Ob, Opart, mpart, lpart);
  attn_reduce_kernel<<<dim3(36, HQ, BB), 256, 0, stream>>>(Opart, mpart, lpart, Ob);
  gemm_o<<<dim3(HID / 128, 64), 256, 0, stream>>>(Ob, WoT, outp);
}